// Round 13
// baseline (151.842 us; speedup 1.0000x reference)
//
#include <hip/hip_runtime.h>

typedef __attribute__((ext_vector_type(4))) float f32x4;
typedef __attribute__((ext_vector_type(8))) short bf16x8;
typedef __attribute__((ext_vector_type(4))) short bf16x4;
typedef long fp8x8;   // 8 packed e4m3 bytes (i64 MFMA operand)

#define NH 4

// round-to-nearest-even f32 -> bf16
static __device__ __forceinline__ unsigned short f2bf(float f){
  unsigned u = __float_as_uint(f);
  u += 0x7FFFu + ((u >> 16) & 1u);
  return (unsigned short)(u >> 16);
}

// pack two f32 -> two bf16 (round-half-up) in one uint (low = a)
static __device__ __forceinline__ unsigned pack2bf(float a, float b){
  return __builtin_amdgcn_perm(__float_as_uint(b) + 0x8000u,
                               __float_as_uint(a) + 0x8000u, 0x07060302u);
}

// pack two f32 -> two bf16 TRUNCATING (1 v_perm). Used only for P: the same
// truncated P feeds both O=P*V and l=sum(P), so the truncation bias cancels.
static __device__ __forceinline__ unsigned pack2bf_t(float a, float b){
  return __builtin_amdgcn_perm(__float_as_uint(b), __float_as_uint(a), 0x07060302u);
}

// pack 4 floats into 4 fp8(e4m3) bytes of one int (byte0 = a)
static __device__ __forceinline__ int pack_fp8x4(float a, float b, float c, float d){
  int w = __builtin_amdgcn_cvt_pk_fp8_f32(a, b, 0, false);
  w     = __builtin_amdgcn_cvt_pk_fp8_f32(c, d, w, true);
  return w;
}

// ---------------- weight-prep kernel (runs once per launch, 4 blocks) ------
// Per head: builds bf16 MFMA fragment-order W in ws + scaled biases.
// WF[h][s][lane][8bf16]:
//   s 0..7  = Wq^T A-frags (s=et*2+ks, pre-scaled S1):
//             lane(quad,l16) = Wq[ks*32+quad*8+j][et*16+l16], j=0..7
//   s 8..15 = Wk^T A-frags (s-8=ft*2+ks, pre-scaled S1): same mapping
//   s 16,17 = Wv B-frags: lane(quad,l16) = Wv[ks*32+quad*8+j][l16]
// bias_s[h][0..63]=bq*S1, [64..127]=bk*S1.
__global__ __launch_bounds__(256) void wprep_kernel(
    const float* __restrict__ Wq, const float* __restrict__ bq,
    const float* __restrict__ Wk, const float* __restrict__ bk,
    const float* __restrict__ Wv,
    unsigned short* __restrict__ WF, float* __restrict__ bias_s, int n)
{
  __shared__ unsigned short wqT[64*72];  // [e][f], stride 72 (16B-aligned rows)
  __shared__ unsigned short wkT[64*72];
  __shared__ unsigned short wvT[16*72];  // [d][f]

  const int t = threadIdx.x;     // 0..255
  const int h = blockIdx.x;
  const float S1 = 0.4246609001f; // sqrt((1/sqrt(64)) * log2(e))
  const int f = t >> 2, eg = t & 3;

  {
    const float4* g = (const float4*)(Wq + h*4096 + f*64 + eg*16);
    #pragma unroll
    for (int p = 0; p < 4; ++p){
      float4 d = g[p];
      int e0 = eg*16 + p*4;
      wqT[(e0+0)*72 + f] = f2bf(d.x * S1);
      wqT[(e0+1)*72 + f] = f2bf(d.y * S1);
      wqT[(e0+2)*72 + f] = f2bf(d.z * S1);
      wqT[(e0+3)*72 + f] = f2bf(d.w * S1);
    }
  }
  {
    const float4* g = (const float4*)(Wk + h*4096 + f*64 + eg*16);
    #pragma unroll
    for (int p = 0; p < 4; ++p){
      float4 d = g[p];
      int e0 = eg*16 + p*4;
      wkT[(e0+0)*72 + f] = f2bf(d.x * S1);
      wkT[(e0+1)*72 + f] = f2bf(d.y * S1);
      wkT[(e0+2)*72 + f] = f2bf(d.z * S1);
      wkT[(e0+3)*72 + f] = f2bf(d.w * S1);
    }
  }
  {
    float4 d = *(const float4*)(Wv + h*1024 + f*16 + eg*4);
    int d0 = eg*4;
    wvT[(d0+0)*72 + f] = f2bf(d.x);
    wvT[(d0+1)*72 + f] = f2bf(d.y);
    wvT[(d0+2)*72 + f] = f2bf(d.z);
    wvT[(d0+3)*72 + f] = f2bf(d.w);
  }
  if (t < 64)       bias_s[h*128 + t] = bq[h*64 + t] * S1;
  else if (t < 128) bias_s[h*128 + t] = bk[h*64 + (t-64)] * S1;
  __syncthreads();

  const int lane = t & 63, w = t >> 6;
  const int quad = lane >> 4, l16 = lane & 15;
  for (int s = w; s < 18; s += 4){
    const unsigned short* src;
    if (s < 8){      int et = s>>1,     ks = s&1;     src = wqT + (et*16+l16)*72 + ks*32 + quad*8; }
    else if (s < 16){int ft = (s-8)>>1, ks = (s-8)&1; src = wkT + (ft*16+l16)*72 + ks*32 + quad*8; }
    else {           int ks = s-16;                   src = wvT + l16*72 + ks*32 + quad*8; }
    uint4 v = *(const uint4*)src;
    *(uint4*)(WF + ((size_t)(h*18 + s)*64 + lane)*8) = v;
  }
}

// ---------------- projection kernel (MFMA) ----------------
// grid (n/64, NH), block 256 = 4 waves. Per wave: Q^T (e-tile w, 4 row-tiles),
// K^T (f-tile w, 4 key-tiles), V (row-tile w). Epilogue writes Qfr/Kt in
// R7-verified fragment-tile order, and Vt in 32-key GROUP fragment order
// matching the K=32 PV A-frag key permutation:
//   Vt[h][g][lane][8bf16], slot (T&1)*4 + reg = V[key=quad*4+reg of tile T]
//   [d=l16]  (tile T=2g -> slots 0..3, T=2g+1 -> slots 4..7).
__global__ __launch_bounds__(256) void proj_kernel(
    const float* __restrict__ x, const float* __restrict__ bv,
    const unsigned short* __restrict__ WF, const float* __restrict__ bias_s,
    unsigned char* __restrict__ Qfr, unsigned char* __restrict__ Kt,
    unsigned short* __restrict__ Vt, int n)
{
  __shared__ unsigned short xf[8*64*8];  // x frags: [it*2+ks][lane][8bf16]
  __shared__ float bql[64], bkl[64], bvl[16];

  const int t  = threadIdx.x;
  const int h  = blockIdx.y;
  const int r0 = blockIdx.x * 64;

  // stage x tile -> bf16 fragment order
  {
    const int r = t >> 2, cg4 = t & 3;
    const float4* g = (const float4*)(x + (size_t)(r0 + r)*64 + cg4*16);
    float4 a = g[0], b = g[1], c = g[2], d = g[3];
    unsigned u0 = pack2bf(a.x,a.y), u1 = pack2bf(a.z,a.w);
    unsigned u2 = pack2bf(b.x,b.y), u3 = pack2bf(b.z,b.w);
    unsigned u4 = pack2bf(c.x,c.y), u5 = pack2bf(c.z,c.w);
    unsigned u6 = pack2bf(d.x,d.y), u7 = pack2bf(d.z,d.w);
    const int it = r >> 4, l16r = r & 15, ks = cg4 >> 1, q0 = (cg4 & 1)*2;
    uint4* dst0 = (uint4*)(xf + ((it*2+ks)*64 + q0*16     + l16r)*8);
    uint4* dst1 = (uint4*)(xf + ((it*2+ks)*64 + (q0+1)*16 + l16r)*8);
    *dst0 = make_uint4(u0,u1,u2,u3);
    *dst1 = make_uint4(u4,u5,u6,u7);
  }
  if (t < 64)        bql[t]     = bias_s[h*128 + t];
  else if (t < 128)  bkl[t-64]  = bias_s[h*128 + t];
  else if (t < 144)  bvl[t-128] = bv[h*16 + (t-128)];
  __syncthreads();

  const int lane = t & 63, w = t >> 6;
  const int quad = lane >> 4, l16 = lane & 15;

  bf16x8 xa[8];
  #pragma unroll
  for (int i = 0; i < 8; ++i)
    xa[i] = *(const bf16x8*)(xf + (i*64 + lane)*8);

  const unsigned short* WFh = WF + (size_t)h*18*64*8;
  bf16x8 wq0 = *(const bf16x8*)(WFh + ((size_t)(     w*2 + 0)*64 + lane)*8);
  bf16x8 wq1 = *(const bf16x8*)(WFh + ((size_t)(     w*2 + 1)*64 + lane)*8);
  bf16x8 wk0 = *(const bf16x8*)(WFh + ((size_t)(8  + w*2 + 0)*64 + lane)*8);
  bf16x8 wk1 = *(const bf16x8*)(WFh + ((size_t)(8  + w*2 + 1)*64 + lane)*8);
  bf16x8 wv0 = *(const bf16x8*)(WFh + ((size_t)16*64 + lane)*8);
  bf16x8 wv1 = *(const bf16x8*)(WFh + ((size_t)17*64 + lane)*8);

  const f32x4 z = {0.f,0.f,0.f,0.f};
  f32x4 accQ[4] = {z,z,z,z};   // Q^T: rows e (tile w), cols Q-row (tile it)
  f32x4 accK[4] = {z,z,z,z};   // K^T: rows f (tile w), cols key (tile tt)
  f32x4 accV = z;

  #pragma unroll
  for (int it = 0; it < 4; ++it){
    accQ[it] = __builtin_amdgcn_mfma_f32_16x16x32_bf16(wq0, xa[it*2+0], accQ[it], 0,0,0);
    accQ[it] = __builtin_amdgcn_mfma_f32_16x16x32_bf16(wq1, xa[it*2+1], accQ[it], 0,0,0);
  }
  #pragma unroll
  for (int tt = 0; tt < 4; ++tt){
    accK[tt] = __builtin_amdgcn_mfma_f32_16x16x32_bf16(wk0, xa[tt*2+0], accK[tt], 0,0,0);
    accK[tt] = __builtin_amdgcn_mfma_f32_16x16x32_bf16(wk1, xa[tt*2+1], accK[tt], 0,0,0);
  }
  accV = __builtin_amdgcn_mfma_f32_16x16x32_bf16(xa[w*2+0], wv0, accV, 0,0,0);
  accV = __builtin_amdgcn_mfma_f32_16x16x32_bf16(xa[w*2+1], wv1, accV, 0,0,0);

  // ---- Q^T tiles: C[e=quad*4+reg (+w*16)][Qrow=l16] -> Qfr frag bytes
  {
    const int e0 = w*16 + quad*4;
    const float b0 = bql[e0], b1 = bql[e0+1], b2 = bql[e0+2], b3 = bql[e0+3];
    const int qk = (e0 & 31) >> 3, hf = e0 >> 5, boff = (quad & 1) * 4;
    #pragma unroll
    for (int it = 0; it < 4; ++it){
      unsigned o = pack_fp8x4(accQ[it][0]+b0, accQ[it][1]+b1,
                              accQ[it][2]+b2, accQ[it][3]+b3);
      const int T = (r0 >> 4) + it;
      *(unsigned*)(Qfr + (size_t)h*((size_t)n<<6) + (size_t)T*1024
                       + (qk*16 + l16)*16 + hf*8 + boff) = o;
    }
  }
  // ---- K^T tiles: C[f=quad*4+reg (+w*16)][key=l16] -> Kt frag bytes
  {
    const int f0 = w*16 + quad*4;
    const float bk0 = bkl[f0], bk1 = bkl[f0+1], bk2 = bkl[f0+2], bk3 = bkl[f0+3];
    const int qk = (f0 & 31) >> 3, hf = f0 >> 5, boff = (quad & 1) * 4;
    #pragma unroll
    for (int tt = 0; tt < 4; ++tt){
      unsigned o = pack_fp8x4(accK[tt][0]+bk0, accK[tt][1]+bk1,
                              accK[tt][2]+bk2, accK[tt][3]+bk3);
      const int T = (r0 >> 4) + tt;
      *(unsigned*)(Kt + (size_t)h*((size_t)n<<6) + (size_t)T*1024
                      + (qk*16 + l16)*16 + hf*8 + boff) = o;
    }
  }
  // ---- V tile (it=w): C[key=quad*4+reg][d=l16] -> group-frag slot (T&1)*4+reg
  {
    float bvv = bvl[l16];
    unsigned v01 = pack2bf(accV[0]+bvv, accV[1]+bvv);
    unsigned v23 = pack2bf(accV[2]+bvv, accV[3]+bvv);
    const int T = (r0 >> 4) + w;
    unsigned short* dst = Vt + (size_t)h*((size_t)n<<4)
                        + (size_t)(T>>1)*512 + lane*8 + (T&1)*4;
    *(uint2*)dst = make_uint2(v01, v23);
  }
}

// ---------------- flash attention kernel ----------------
// grid (n/32)*NH, block 512 = 8 waves = jq 0..7 (key split 8-way), all waves
// share the block's 32 Q-rows; 4 blocks/CU -> 8 waves/SIMD. All loads dense.
// R13 (serial-issue model: time ~= MFMA busy + VALU busy; R12 reorder was
// neutral, R10 op-removal was proportional):
//  - la (ones) MFMAs removed: row sums via 14 VALU adds/group + 2 epilogue
//    shuffles (-38.8 MFMA cy/tile, +14 VALU).
//  - PV via mfma_f32_16x16x32_bf16: ONE instr per 32-key group per i-tile.
//    A-frag slots k=quad*8+j = [tile-a pc | tile-b pc] (no cross-lane: key
//    order within a group is a free permutation, and proj writes Vt in the
//    matching group layout). Halves PV instr count and V loads.
__global__ __launch_bounds__(512, 8) void attn_kernel(
    const unsigned char* __restrict__ Qfr, const unsigned char* __restrict__ Kt,
    const unsigned short* __restrict__ Vt, float* __restrict__ out, int n)
{
  __shared__ float part[7][64][11];   // padded stride 11: conflict-light merge

  const int tid  = threadIdx.x;
  const int lane = tid & 63;
  const int jq   = tid >> 6;     // 0..7: key-range octant
  const int bid  = blockIdx.x;
  const int h    = bid & 3;
  const int iblk = bid >> 2;
  const int l16  = lane & 15, quad = lane >> 4;
  const int i0   = iblk*32;
  const int ngq  = (n >> 3) >> 5;            // 32-key groups per octant (32)

  // Q fragments: 2 i-tiles x 2 e-halves -- DENSE (one uint4 per i-tile)
  const unsigned char* qfh = Qfr + (size_t)h*((size_t)n<<6);
  longlong2 q0 = *(const longlong2*)(qfh + (size_t)((i0>>4)    )*1024 + lane*16);
  longlong2 q1 = *(const longlong2*)(qfh + (size_t)((i0>>4) + 1)*1024 + lane*16);
  const fp8x8 qf00 = (fp8x8)q0.x;
  const fp8x8 qf01 = (fp8x8)q0.y;
  const fp8x8 qf10 = (fp8x8)q1.x;
  const fp8x8 qf11 = (fp8x8)q1.y;

  const longlong2* ktl = (const longlong2*)(Kt + (size_t)h*((size_t)n<<6))
                       + (size_t)(jq*ngq)*128 + lane;
  const uint4*     vtu = (const uint4*)(Vt + (size_t)h*((size_t)n<<4))
                       + (size_t)(jq*ngq)*64 + lane;

  f32x4 o0 = {0.f,0.f,0.f,0.f};
  f32x4 o1 = {0.f,0.f,0.f,0.f};
  float ls0 = 0.f, ls1 = 0.f;
  const f32x4 z = {0.f,0.f,0.f,0.f};

// process one 32-key group: K tiles (KT0,KT1), V group-frag VG
#define PROC_GROUP(KT0, KT1, VG)                                              \
  {                                                                           \
    fp8x8 ak0 = (fp8x8)KT0.x, ak1 = (fp8x8)KT0.y;                             \
    fp8x8 bk0 = (fp8x8)KT1.x, bk1 = (fp8x8)KT1.y;                             \
    f32x4 sa0 = __builtin_amdgcn_mfma_f32_16x16x32_fp8_fp8(ak0, qf00, z,0,0,0);\
    sa0 = __builtin_amdgcn_mfma_f32_16x16x32_fp8_fp8(ak1, qf01, sa0, 0,0,0);  \
    f32x4 sa1 = __builtin_amdgcn_mfma_f32_16x16x32_fp8_fp8(ak0, qf10, z,0,0,0);\
    sa1 = __builtin_amdgcn_mfma_f32_16x16x32_fp8_fp8(ak1, qf11, sa1, 0,0,0);  \
    f32x4 sb0 = __builtin_amdgcn_mfma_f32_16x16x32_fp8_fp8(bk0, qf00, z,0,0,0);\
    sb0 = __builtin_amdgcn_mfma_f32_16x16x32_fp8_fp8(bk1, qf01, sb0, 0,0,0);  \
    f32x4 sb1 = __builtin_amdgcn_mfma_f32_16x16x32_fp8_fp8(bk0, qf10, z,0,0,0);\
    sb1 = __builtin_amdgcn_mfma_f32_16x16x32_fp8_fp8(bk1, qf11, sb1, 0,0,0);  \
    float pa00 = __builtin_amdgcn_exp2f(sa0[0]);                              \
    float pa01 = __builtin_amdgcn_exp2f(sa0[1]);                              \
    float pa02 = __builtin_amdgcn_exp2f(sa0[2]);                              \
    float pa03 = __builtin_amdgcn_exp2f(sa0[3]);                              \
    float pa10 = __builtin_amdgcn_exp2f(sa1[0]);                              \
    float pa11 = __builtin_amdgcn_exp2f(sa1[1]);                              \
    float pa12 = __builtin_amdgcn_exp2f(sa1[2]);                              \
    float pa13 = __builtin_amdgcn_exp2f(sa1[3]);                              \
    float pb00 = __builtin_amdgcn_exp2f(sb0[0]);                              \
    float pb01 = __builtin_amdgcn_exp2f(sb0[1]);                              \
    float pb02 = __builtin_amdgcn_exp2f(sb0[2]);                              \
    float pb03 = __builtin_amdgcn_exp2f(sb0[3]);                              \
    float pb10 = __builtin_amdgcn_exp2f(sb1[0]);                              \
    float pb11 = __builtin_amdgcn_exp2f(sb1[1]);                              \
    float pb12 = __builtin_amdgcn_exp2f(sb1[2]);                              \
    float pb13 = __builtin_amdgcn_exp2f(sb1[3]);                              \
    ls0 += ((pa00 + pa01) + (pa02 + pa03)) + ((pb00 + pb01) + (pb02 + pb03)); \
    ls1 += ((pa10 + pa11) + (pa12 + pa13)) + ((pb10 + pb11) + (pb12 + pb13)); \
    union { unsigned u[4]; bf16x8 v; } af0, af1;                              \
    af0.u[0] = pack2bf_t(pa00,pa01); af0.u[1] = pack2bf_t(pa02,pa03);         \
    af0.u[2] = pack2bf_t(pb00,pb01); af0.u[3] = pack2bf_t(pb02,pb03);         \
    af1.u[0] = pack2bf_t(pa10,pa11); af1.u[1] = pack2bf_t(pa12,pa13);         \
    af1.u[2] = pack2bf_t(pb10,pb11); af1.u[3] = pack2bf_t(pb12,pb13);         \
    bf16x8 vgf; { union { uint4 u; bf16x8 v; } c; c.u = VG; vgf = c.v; }      \
    o0 = __builtin_amdgcn_mfma_f32_16x16x32_bf16(af0.v, vgf, o0, 0,0,0);      \
    o1 = __builtin_amdgcn_mfma_f32_16x16x32_bf16(af1.v, vgf, o1, 0,0,0);      \
  }

  // pipeline: 2 groups in flight, prefetch distance 2 groups
  longlong2 kA0 = ktl[0],   kA1 = ktl[64];
  uint4     vA  = vtu[0];
  longlong2 kB0 = ktl[128], kB1 = ktl[192];
  uint4     vB  = vtu[64];

  for (int g = 0; g < ngq - 2; g += 2){
    longlong2 kC0 = ktl[256], kC1 = ktl[320];
    uint4     vC  = vtu[128];
    longlong2 kD0 = ktl[384], kD1 = ktl[448];
    uint4     vD  = vtu[192];
    PROC_GROUP(kA0, kA1, vA)
    PROC_GROUP(kB0, kB1, vB)
    kA0 = kC0; kA1 = kC1; vA = vC;
    kB0 = kD0; kB1 = kD1; vB = vD;
    ktl += 256; vtu += 128;
  }
  PROC_GROUP(kA0, kA1, vA)
  PROC_GROUP(kB0, kB1, vB)
#undef PROC_GROUP

  // full octant row sums: reduce partials across quads (rows i = l16)
  ls0 += __shfl_xor(ls0, 16); ls0 += __shfl_xor(ls0, 32);
  ls1 += __shfl_xor(ls1, 16); ls1 += __shfl_xor(ls1, 32);

  if (jq > 0){
    float* p = &part[jq-1][lane][0];
    p[0]=o0[0]; p[1]=o0[1]; p[2]=o0[2]; p[3]=o0[3];
    p[4]=o1[0]; p[5]=o1[1]; p[6]=o1[2]; p[7]=o1[3];
    p[8]=ls0;   p[9]=ls1;
  }
  __syncthreads();

  if (jq == 0){
    #pragma unroll
    for (int q = 0; q < 7; ++q){
      const float* r = &part[q][lane][0];
      o0[0]+=r[0]; o0[1]+=r[1]; o0[2]+=r[2]; o0[3]+=r[3];
      o1[0]+=r[4]; o1[1]+=r[5]; o1[2]+=r[6]; o1[3]+=r[7];
      ls0 += r[8]; ls1 += r[9];
    }
    float inv0 = 1.0f / ls0;
    float inv1 = 1.0f / ls1;
    #pragma unroll
    for (int reg = 0; reg < 4; ++reg){
      int i = quad*4 + reg;
      float a0 = __shfl(inv0, i);   // inv for Q-row i lives at lane i (l16=i)
      float a1 = __shfl(inv1, i);
      out[(size_t)(i0 + i)*64      + h*16 + l16] = o0[reg] * a0;
      out[(size_t)(i0 + 16 + i)*64 + h*16 + l16] = o1[reg] * a1;
    }
  }
}

extern "C" void kernel_launch(void* const* d_in, const int* in_sizes, int n_in,
                              void* d_out, int out_size, void* d_ws, size_t ws_size,
                              hipStream_t stream) {
  const float* x  = (const float*)d_in[0];
  const float* Wq = (const float*)d_in[1];
  const float* bq = (const float*)d_in[2];
  const float* Wk = (const float*)d_in[3];
  const float* bk = (const float*)d_in[4];
  const float* Wv = (const float*)d_in[5];
  const float* bv = (const float*)d_in[6];
  float* out = (float*)d_out;

  const int n = in_sizes[0] / 64;   // 8192

  unsigned char* Qfr  = (unsigned char*)d_ws;                       // NH*n*64 B frag tiles (Q)
  unsigned char* Kt   = Qfr + (size_t)NH*n*64;                      // NH*n*64 B frag tiles (K)
  unsigned short* Vt  = (unsigned short*)(Kt + (size_t)NH*n*64);    // NH*n*16 u16 group frags
  unsigned short* WF  = Vt + (size_t)NH*n*16;                       // NH*18*64*8 u16 frags
  float* bias_s       = (float*)(WF + (size_t)NH*18*64*8);          // NH*128 f32

  wprep_kernel<<<NH, 256, 0, stream>>>(Wq, bq, Wk, bk, Wv, WF, bias_s, n);
  proj_kernel<<<dim3(n/64, NH), 256, 0, stream>>>(x, bv, WF, bias_s, Qfr, Kt, Vt, n);
  attn_kernel<<<dim3((n/32)*NH), 512, 0, stream>>>(Qfr, Kt, Vt, out, n);
}

// Round 15
// 121.215 us; speedup vs baseline: 1.2527x; 1.2527x over previous
//
#include <hip/hip_runtime.h>

typedef __attribute__((ext_vector_type(4))) float f32x4;
typedef __attribute__((ext_vector_type(8))) short bf16x8;
typedef __attribute__((ext_vector_type(4))) short bf16x4;
typedef long fp8x8;   // 8 packed e4m3 bytes (i64 MFMA operand)

#define NH 4

// round-to-nearest-even f32 -> bf16
static __device__ __forceinline__ unsigned short f2bf(float f){
  unsigned u = __float_as_uint(f);
  u += 0x7FFFu + ((u >> 16) & 1u);
  return (unsigned short)(u >> 16);
}

// pack two f32 -> two bf16 (round-half-up) in one uint (low = a)
static __device__ __forceinline__ unsigned pack2bf(float a, float b){
  return __builtin_amdgcn_perm(__float_as_uint(b) + 0x8000u,
                               __float_as_uint(a) + 0x8000u, 0x07060302u);
}

// pack two f32 -> two bf16 TRUNCATING (1 v_perm). Used only for P: the same
// truncated P feeds both O=P*V and l=P*1, so the truncation bias cancels.
static __device__ __forceinline__ unsigned pack2bf_t(float a, float b){
  return __builtin_amdgcn_perm(__float_as_uint(b), __float_as_uint(a), 0x07060302u);
}

// pack 4 floats into 4 fp8(e4m3) bytes of one int (byte0 = a)
static __device__ __forceinline__ int pack_fp8x4(float a, float b, float c, float d){
  int w = __builtin_amdgcn_cvt_pk_fp8_f32(a, b, 0, false);
  w     = __builtin_amdgcn_cvt_pk_fp8_f32(c, d, w, true);
  return w;
}

// ---------------- weight-prep kernel (runs once per launch, 4 blocks) ------
// Per head: builds bf16 MFMA fragment-order W in ws + scaled biases.
// WF[h][s][lane][8bf16]:
//   s 0..7  = Wq^T A-frags (s=et*2+ks, pre-scaled S1):
//             lane(quad,l16) = Wq[ks*32+quad*8+j][et*16+l16], j=0..7
//   s 8..15 = Wk^T A-frags (s-8=ft*2+ks, pre-scaled S1): same mapping
//   s 16,17 = Wv B-frags: lane(quad,l16) = Wv[ks*32+quad*8+j][l16]
// bias_s[h][0..63]=bq*S1, [64..127]=bk*S1.
__global__ __launch_bounds__(256) void wprep_kernel(
    const float* __restrict__ Wq, const float* __restrict__ bq,
    const float* __restrict__ Wk, const float* __restrict__ bk,
    const float* __restrict__ Wv,
    unsigned short* __restrict__ WF, float* __restrict__ bias_s, int n)
{
  __shared__ unsigned short wqT[64*72];  // [e][f], stride 72 (16B-aligned rows)
  __shared__ unsigned short wkT[64*72];
  __shared__ unsigned short wvT[16*72];  // [d][f]

  const int t = threadIdx.x;     // 0..255
  const int h = blockIdx.x;
  const float S1 = 0.4246609001f; // sqrt((1/sqrt(64)) * log2(e))
  const int f = t >> 2, eg = t & 3;

  {
    const float4* g = (const float4*)(Wq + h*4096 + f*64 + eg*16);
    #pragma unroll
    for (int p = 0; p < 4; ++p){
      float4 d = g[p];
      int e0 = eg*16 + p*4;
      wqT[(e0+0)*72 + f] = f2bf(d.x * S1);
      wqT[(e0+1)*72 + f] = f2bf(d.y * S1);
      wqT[(e0+2)*72 + f] = f2bf(d.z * S1);
      wqT[(e0+3)*72 + f] = f2bf(d.w * S1);
    }
  }
  {
    const float4* g = (const float4*)(Wk + h*4096 + f*64 + eg*16);
    #pragma unroll
    for (int p = 0; p < 4; ++p){
      float4 d = g[p];
      int e0 = eg*16 + p*4;
      wkT[(e0+0)*72 + f] = f2bf(d.x * S1);
      wkT[(e0+1)*72 + f] = f2bf(d.y * S1);
      wkT[(e0+2)*72 + f] = f2bf(d.z * S1);
      wkT[(e0+3)*72 + f] = f2bf(d.w * S1);
    }
  }
  {
    float4 d = *(const float4*)(Wv + h*1024 + f*16 + eg*4);
    int d0 = eg*4;
    wvT[(d0+0)*72 + f] = f2bf(d.x);
    wvT[(d0+1)*72 + f] = f2bf(d.y);
    wvT[(d0+2)*72 + f] = f2bf(d.z);
    wvT[(d0+3)*72 + f] = f2bf(d.w);
  }
  if (t < 64)       bias_s[h*128 + t] = bq[h*64 + t] * S1;
  else if (t < 128) bias_s[h*128 + t] = bk[h*64 + (t-64)] * S1;
  __syncthreads();

  const int lane = t & 63, w = t >> 6;
  const int quad = lane >> 4, l16 = lane & 15;
  for (int s = w; s < 18; s += 4){
    const unsigned short* src;
    if (s < 8){      int et = s>>1,     ks = s&1;     src = wqT + (et*16+l16)*72 + ks*32 + quad*8; }
    else if (s < 16){int ft = (s-8)>>1, ks = (s-8)&1; src = wkT + (ft*16+l16)*72 + ks*32 + quad*8; }
    else {           int ks = s-16;                   src = wvT + l16*72 + ks*32 + quad*8; }
    uint4 v = *(const uint4*)src;
    *(uint4*)(WF + ((size_t)(h*18 + s)*64 + lane)*8) = v;
  }
}

// ---------------- projection kernel (MFMA) ----------------
// grid (n/64, NH), block 256 = 4 waves. Per wave: Q^T (e-tile w, 4 row-tiles),
// K^T (f-tile w, 4 key-tiles), V (row-tile w). Epilogue writes Qfr/Kt/Vt in
// fragment-tile order so ALL attn hot/prologue loads are dense.
__global__ __launch_bounds__(256) void proj_kernel(
    const float* __restrict__ x, const float* __restrict__ bv,
    const unsigned short* __restrict__ WF, const float* __restrict__ bias_s,
    unsigned char* __restrict__ Qfr, unsigned char* __restrict__ Kt,
    unsigned short* __restrict__ Vt, int n)
{
  __shared__ unsigned short xf[8*64*8];  // x frags: [it*2+ks][lane][8bf16]
  __shared__ float bql[64], bkl[64], bvl[16];

  const int t  = threadIdx.x;
  const int h  = blockIdx.y;
  const int r0 = blockIdx.x * 64;

  // stage x tile -> bf16 fragment order
  {
    const int r = t >> 2, cg4 = t & 3;
    const float4* g = (const float4*)(x + (size_t)(r0 + r)*64 + cg4*16);
    float4 a = g[0], b = g[1], c = g[2], d = g[3];
    unsigned u0 = pack2bf(a.x,a.y), u1 = pack2bf(a.z,a.w);
    unsigned u2 = pack2bf(b.x,b.y), u3 = pack2bf(b.z,b.w);
    unsigned u4 = pack2bf(c.x,c.y), u5 = pack2bf(c.z,c.w);
    unsigned u6 = pack2bf(d.x,d.y), u7 = pack2bf(d.z,d.w);
    const int it = r >> 4, l16r = r & 15, ks = cg4 >> 1, q0 = (cg4 & 1)*2;
    uint4* dst0 = (uint4*)(xf + ((it*2+ks)*64 + q0*16     + l16r)*8);
    uint4* dst1 = (uint4*)(xf + ((it*2+ks)*64 + (q0+1)*16 + l16r)*8);
    *dst0 = make_uint4(u0,u1,u2,u3);
    *dst1 = make_uint4(u4,u5,u6,u7);
  }
  if (t < 64)        bql[t]     = bias_s[h*128 + t];
  else if (t < 128)  bkl[t-64]  = bias_s[h*128 + t];
  else if (t < 144)  bvl[t-128] = bv[h*16 + (t-128)];
  __syncthreads();

  const int lane = t & 63, w = t >> 6;
  const int quad = lane >> 4, l16 = lane & 15;

  bf16x8 xa[8];
  #pragma unroll
  for (int i = 0; i < 8; ++i)
    xa[i] = *(const bf16x8*)(xf + (i*64 + lane)*8);

  const unsigned short* WFh = WF + (size_t)h*18*64*8;
  bf16x8 wq0 = *(const bf16x8*)(WFh + ((size_t)(     w*2 + 0)*64 + lane)*8);
  bf16x8 wq1 = *(const bf16x8*)(WFh + ((size_t)(     w*2 + 1)*64 + lane)*8);
  bf16x8 wk0 = *(const bf16x8*)(WFh + ((size_t)(8  + w*2 + 0)*64 + lane)*8);
  bf16x8 wk1 = *(const bf16x8*)(WFh + ((size_t)(8  + w*2 + 1)*64 + lane)*8);
  bf16x8 wv0 = *(const bf16x8*)(WFh + ((size_t)16*64 + lane)*8);
  bf16x8 wv1 = *(const bf16x8*)(WFh + ((size_t)17*64 + lane)*8);

  const f32x4 z = {0.f,0.f,0.f,0.f};
  f32x4 accQ[4] = {z,z,z,z};   // Q^T: rows e (tile w), cols Q-row (tile it)
  f32x4 accK[4] = {z,z,z,z};   // K^T: rows f (tile w), cols key (tile tt)
  f32x4 accV = z;

  #pragma unroll
  for (int it = 0; it < 4; ++it){
    accQ[it] = __builtin_amdgcn_mfma_f32_16x16x32_bf16(wq0, xa[it*2+0], accQ[it], 0,0,0);
    accQ[it] = __builtin_amdgcn_mfma_f32_16x16x32_bf16(wq1, xa[it*2+1], accQ[it], 0,0,0);
  }
  #pragma unroll
  for (int tt = 0; tt < 4; ++tt){
    accK[tt] = __builtin_amdgcn_mfma_f32_16x16x32_bf16(wk0, xa[tt*2+0], accK[tt], 0,0,0);
    accK[tt] = __builtin_amdgcn_mfma_f32_16x16x32_bf16(wk1, xa[tt*2+1], accK[tt], 0,0,0);
  }
  accV = __builtin_amdgcn_mfma_f32_16x16x32_bf16(xa[w*2+0], wv0, accV, 0,0,0);
  accV = __builtin_amdgcn_mfma_f32_16x16x32_bf16(xa[w*2+1], wv1, accV, 0,0,0);

  // ---- Q^T tiles: C[e=quad*4+reg (+w*16)][Qrow=l16] -> Qfr frag bytes
  {
    const int e0 = w*16 + quad*4;
    const float b0 = bql[e0], b1 = bql[e0+1], b2 = bql[e0+2], b3 = bql[e0+3];
    const int qk = (e0 & 31) >> 3, hf = e0 >> 5, boff = (quad & 1) * 4;
    #pragma unroll
    for (int it = 0; it < 4; ++it){
      unsigned o = pack_fp8x4(accQ[it][0]+b0, accQ[it][1]+b1,
                              accQ[it][2]+b2, accQ[it][3]+b3);
      const int T = (r0 >> 4) + it;
      *(unsigned*)(Qfr + (size_t)h*((size_t)n<<6) + (size_t)T*1024
                       + (qk*16 + l16)*16 + hf*8 + boff) = o;
    }
  }
  // ---- K^T tiles: C[f=quad*4+reg (+w*16)][key=l16] -> Kt frag bytes
  {
    const int f0 = w*16 + quad*4;
    const float bk0 = bkl[f0], bk1 = bkl[f0+1], bk2 = bkl[f0+2], bk3 = bkl[f0+3];
    const int qk = (f0 & 31) >> 3, hf = f0 >> 5, boff = (quad & 1) * 4;
    #pragma unroll
    for (int tt = 0; tt < 4; ++tt){
      unsigned o = pack_fp8x4(accK[tt][0]+bk0, accK[tt][1]+bk1,
                              accK[tt][2]+bk2, accK[tt][3]+bk3);
      const int T = (r0 >> 4) + tt;
      *(unsigned*)(Kt + (size_t)h*((size_t)n<<6) + (size_t)T*1024
                      + (qk*16 + l16)*16 + hf*8 + boff) = o;
    }
  }
  // ---- V tile (it=w): C[key=quad*4+reg][d=l16] == Vt lane(quad,l16), j=reg. DENSE.
  {
    float bvv = bvl[l16];
    unsigned v01 = pack2bf(accV[0]+bvv, accV[1]+bvv);
    unsigned v23 = pack2bf(accV[2]+bvv, accV[3]+bvv);
    const int T = (r0 >> 4) + w;
    *(uint2*)(Vt + (size_t)h*((size_t)n<<4) + ((size_t)T*64 + lane)*4) = make_uint2(v01, v23);
  }
}

// ---------------- flash attention kernel ----------------
// grid (n/32)*NH, block 512 = 8 waves = jq 0..7 (key split 8-way), all waves
// share the block's 32 Q-rows. 4 blocks/CU -> 8 waves/SIMD. All loads dense
// (fragment-ordered Qfr/Kt/Vt). Max-free online softmax; row sums via
// ones-MFMA (C-layout == O). VALU diet (R10): longlong2 K loads (no shift/or
// reassembly), truncating P pack (1 v_perm), tail-split loop (no clamp).
// [R15 = R10 verbatim: best verified kernel. R11 poly-exp (-68%), R12
// interleave (neutral), R13/R14 K=32-PV (spills + post-timing divergence)
// all failed to beat it. Issue-port bound: VALUBusy 55 + MfmaUtil 57.]
__global__ __launch_bounds__(512, 8) void attn_kernel(
    const unsigned char* __restrict__ Qfr, const unsigned char* __restrict__ Kt,
    const unsigned short* __restrict__ Vt, float* __restrict__ out, int n)
{
  __shared__ float part[7][64][17];   // 30.5 KB padded

  const int tid  = threadIdx.x;
  const int lane = tid & 63;
  const int jq   = tid >> 6;     // 0..7: key-range octant
  const int bid  = blockIdx.x;
  const int h    = bid & 3;
  const int iblk = bid >> 2;
  const int l16  = lane & 15, quad = lane >> 4;
  const int i0   = iblk*32;
  const int ntq  = (n >> 3) >> 4;            // tiles per octant (64)
  const int tile0 = jq * ntq;

  // Q fragments: 2 i-tiles x 2 e-halves -- DENSE (one uint4 per i-tile)
  const unsigned char* qfh = Qfr + (size_t)h*((size_t)n<<6);
  longlong2 q0 = *(const longlong2*)(qfh + (size_t)((i0>>4)    )*1024 + lane*16);
  longlong2 q1 = *(const longlong2*)(qfh + (size_t)((i0>>4) + 1)*1024 + lane*16);
  const fp8x8 qf00 = (fp8x8)q0.x;
  const fp8x8 qf01 = (fp8x8)q0.y;
  const fp8x8 qf10 = (fp8x8)q1.x;
  const fp8x8 qf11 = (fp8x8)q1.y;

  const longlong2* ktl = (const longlong2*)(Kt + (size_t)h*((size_t)n<<6)) + (size_t)tile0*64 + lane;
  const uint2*     vtu = (const uint2*)(Vt + (size_t)h*((size_t)n<<4)) + (size_t)tile0*64 + lane;

  f32x4 o0  = {0.f,0.f,0.f,0.f};
  f32x4 o1  = {0.f,0.f,0.f,0.f};
  f32x4 la0 = {0.f,0.f,0.f,0.f};
  f32x4 la1 = {0.f,0.f,0.f,0.f};
  const f32x4 z = {0.f,0.f,0.f,0.f};
  const bf16x4 vones = {(short)0x3F80, (short)0x3F80, (short)0x3F80, (short)0x3F80};

  longlong2 ka = ktl[0];
  uint2     va = vtu[0];
  longlong2 kb = ktl[64];
  uint2     vb = vtu[64];

#define ATTN_TILE(KK, VV)                                                     \
  {                                                                           \
    fp8x8 k0 = (fp8x8)KK.x;                                                   \
    fp8x8 k1 = (fp8x8)KK.y;                                                   \
    bf16x4 vf; { union { uint2 u; bf16x4 v; } c; c.u = VV; vf = c.v; }        \
    f32x4 s0 = __builtin_amdgcn_mfma_f32_16x16x32_fp8_fp8(k0, qf00, z, 0,0,0);\
    s0 = __builtin_amdgcn_mfma_f32_16x16x32_fp8_fp8(k1, qf01, s0, 0,0,0);     \
    f32x4 s1 = __builtin_amdgcn_mfma_f32_16x16x32_fp8_fp8(k0, qf10, z, 0,0,0);\
    s1 = __builtin_amdgcn_mfma_f32_16x16x32_fp8_fp8(k1, qf11, s1, 0,0,0);     \
    float p00 = __builtin_amdgcn_exp2f(s0[0]);                                \
    float p01 = __builtin_amdgcn_exp2f(s0[1]);                                \
    float p02 = __builtin_amdgcn_exp2f(s0[2]);                                \
    float p03 = __builtin_amdgcn_exp2f(s0[3]);                                \
    float p10 = __builtin_amdgcn_exp2f(s1[0]);                                \
    float p11 = __builtin_amdgcn_exp2f(s1[1]);                                \
    float p12 = __builtin_amdgcn_exp2f(s1[2]);                                \
    float p13 = __builtin_amdgcn_exp2f(s1[3]);                                \
    union { uint2 u; bf16x4 v; } pc0, pc1;                                    \
    pc0.u = make_uint2(pack2bf_t(p00,p01), pack2bf_t(p02,p03));               \
    pc1.u = make_uint2(pack2bf_t(p10,p11), pack2bf_t(p12,p13));               \
    o0  = __builtin_amdgcn_mfma_f32_16x16x16bf16_1k(pc0.v, vf,    o0,  0,0,0);\
    o1  = __builtin_amdgcn_mfma_f32_16x16x16bf16_1k(pc1.v, vf,    o1,  0,0,0);\
    la0 = __builtin_amdgcn_mfma_f32_16x16x16bf16_1k(pc0.v, vones, la0, 0,0,0);\
    la1 = __builtin_amdgcn_mfma_f32_16x16x16bf16_1k(pc1.v, vones, la1, 0,0,0);\
  }

  // main loop: prefetch 2 tiles ahead at fixed offsets, pointer bump
  for (int tt = 0; tt < ntq - 2; tt += 2){
    longlong2 kc = ktl[128];
    uint2     vc = vtu[128];
    longlong2 kd = ktl[192];
    uint2     vd = vtu[192];
    ATTN_TILE(ka, va)
    ATTN_TILE(kb, vb)
    ka = kc; va = vc;
    kb = kd; vb = vd;
    ktl += 128; vtu += 128;
  }
  // tail: last two tiles, no prefetch
  ATTN_TILE(ka, va)
  ATTN_TILE(kb, vb)
#undef ATTN_TILE

  if (jq > 0){
    float* p = &part[jq-1][lane][0];
    p[ 0]=o0[0];  p[ 1]=o0[1];  p[ 2]=o0[2];  p[ 3]=o0[3];
    p[ 4]=o1[0];  p[ 5]=o1[1];  p[ 6]=o1[2];  p[ 7]=o1[3];
    p[ 8]=la0[0]; p[ 9]=la0[1]; p[10]=la0[2]; p[11]=la0[3];
    p[12]=la1[0]; p[13]=la1[1]; p[14]=la1[2]; p[15]=la1[3];
  }
  __syncthreads();

  if (jq == 0){
    #pragma unroll
    for (int q = 0; q < 7; ++q){
      const float* r = &part[q][lane][0];
      o0[0] +=r[0];  o0[1] +=r[1];  o0[2] +=r[2];  o0[3] +=r[3];
      o1[0] +=r[4];  o1[1] +=r[5];  o1[2] +=r[6];  o1[3] +=r[7];
      la0[0]+=r[8];  la0[1]+=r[9];  la0[2]+=r[10]; la0[3]+=r[11];
      la1[0]+=r[12]; la1[1]+=r[13]; la1[2]+=r[14]; la1[3]+=r[15];
    }
    #pragma unroll
    for (int reg = 0; reg < 4; ++reg){
      int i = quad*4 + reg;
      out[(size_t)(i0 + i)*64      + h*16 + l16] = o0[reg] / la0[reg];
      out[(size_t)(i0 + 16 + i)*64 + h*16 + l16] = o1[reg] / la1[reg];
    }
  }
}

extern "C" void kernel_launch(void* const* d_in, const int* in_sizes, int n_in,
                              void* d_out, int out_size, void* d_ws, size_t ws_size,
                              hipStream_t stream) {
  const float* x  = (const float*)d_in[0];
  const float* Wq = (const float*)d_in[1];
  const float* bq = (const float*)d_in[2];
  const float* Wk = (const float*)d_in[3];
  const float* bk = (const float*)d_in[4];
  const float* Wv = (const float*)d_in[5];
  const float* bv = (const float*)d_in[6];
  float* out = (float*)d_out;

  const int n = in_sizes[0] / 64;   // 8192

  unsigned char* Qfr  = (unsigned char*)d_ws;                       // NH*n*64 B frag tiles (Q)
  unsigned char* Kt   = Qfr + (size_t)NH*n*64;                      // NH*n*64 B frag tiles (K)
  unsigned short* Vt  = (unsigned short*)(Kt + (size_t)NH*n*64);    // NH*n*16 u16 frag tiles
  unsigned short* WF  = Vt + (size_t)NH*n*16;                       // NH*18*64*8 u16 frags
  float* bias_s       = (float*)(WF + (size_t)NH*18*64*8);          // NH*128 f32

  wprep_kernel<<<NH, 256, 0, stream>>>(Wq, bq, Wk, bk, Wv, WF, bias_s, n);
  proj_kernel<<<dim3(n/64, NH), 256, 0, stream>>>(x, bv, WF, bias_s, Qfr, Kt, Vt, n);
  attn_kernel<<<dim3((n/32)*NH), 512, 0, stream>>>(Qfr, Kt, Vt, out, n);
}